// Round 3
// baseline (4798.491 us; speedup 1.0000x reference)
//
#include <hip/hip_runtime.h>

#define BB 512
#define TT 2048
#define DD 8
#define HH 64

__device__ __forceinline__ float rl(float v, int l) {
  return __int_as_float(__builtin_amdgcn_readlane(__float_as_int(v), l));
}
__device__ __forceinline__ float sigm(float x) {
  return 1.0f / (1.0f + __expf(-x));
}
__device__ __forceinline__ float tanh_fast(float x) {
  // tanh(x) = 1 - 2/(exp(2x)+1); saturates correctly at +/-inf
  return 1.0f - 2.0f / (__expf(2.0f * x) + 1.0f);
}
__device__ __forceinline__ float2 pk_fma(float2 a, float2 b, float2 c) {
  float2 r;
  r.x = fmaf(a.x, b.x, c.x);
  r.y = fmaf(a.y, b.y, c.y);
  return r;
}

// 512 threads/block, one batch element per block. Thread (half=tid>>8,
// g=tid&255) owns k-range [32*half, 32*half+32) of gate row g for
// whh0/wih1/whh1 (+4 cols of wih0) = 100 weight floats -> ~123 live VGPRs,
// under the 128-VGPR / 4-waves-per-EU class the allocator insists on
// (rounds 1-2: asking for 256 VGPRs was ignored -> 108 VGPRs + 34 GB of
// scratch-spill HBM traffic). Partials combine via 1-float LDS writes;
// every thread redundantly computes its lane's 4 gate activations so a step
// needs only 2 barriers. Wave-replicated h/c state; h broadcasts via
// v_readlane with compile-time lane indices (wave-uniform branch on half).
__global__ void __launch_bounds__(512)
    __attribute__((amdgpu_waves_per_eu(4, 4)))
    lstm2_fused(
        const float* __restrict__ x,
        const float* __restrict__ w_ih0, const float* __restrict__ w_hh0,
        const float* __restrict__ b_ih0, const float* __restrict__ b_hh0,
        const float* __restrict__ w_ih1, const float* __restrict__ w_hh1,
        const float* __restrict__ b_ih1, const float* __restrict__ b_hh1,
        const float* __restrict__ w_out, const float* __restrict__ b_out,
        float* __restrict__ out)
{
  const int b    = blockIdx.x;
  const int tid  = threadIdx.x;
  const int g    = tid & 255;   // gate row
  const int half = tid >> 8;    // k-range selector
  const int lane = tid & 63;
  const int kb   = half * 32;

  __shared__ float part0[512];  // [half][gate] partial preactivations, layer 0
  __shared__ float part1[512];  // layer 1

  // ---- one-time: this thread's half-rows into registers ----
  float  wx[4];
  float2 w01[32];  // (wih1[k], whh0[k]) share the h0 broadcast -> pk_fma
  float  w11[32];  // whh1[k]
#pragma unroll
  for (int j = 0; j < 4; ++j) wx[j] = w_ih0[g * DD + half * 4 + j];
#pragma unroll
  for (int k = 0; k < 32; ++k) {
    w01[k] = make_float2(w_ih1[g * HH + kb + k], w_hh0[g * HH + kb + k]);
    w11[k] = w_hh1[g * HH + kb + k];
  }
  // biases folded into half-0's partial only
  const float bias0 = (half == 0) ? (b_ih0[g] + b_hh0[g]) : 0.0f;
  const float bias1 = (half == 0) ? (b_ih1[g] + b_hh1[g]) : 0.0f;

  // per-wave replicated state: lane j holds element j
  float h0 = 0.0f, c0 = 0.0f, h1 = 0.0f, c1 = 0.0f;
  // carried partial of layer-0 preactivation: bias0 + (my k-range of Whh0.h0)
  float carry = bias0;

  const float* xb = x + (size_t)b * TT * DD + half * 4;
  float4 xq = *(const float4*)xb;  // x[t=0], this half's 4 columns

#define PHASE_C(KB)                                          \
  _Pragma("unroll")                                          \
  for (int k = 0; k < 32; ++k) {                             \
    const float h0k = rl(h0, (KB) + k);                      \
    const float h1k = rl(h1, (KB) + k);                      \
    a01 = pk_fma(w01[k], make_float2(h0k, h0k), a01);        \
    p1b = fmaf(w11[k], h1k, p1b);                            \
  }

  for (int t = 0; t < TT; ++t) {
    // ---- phase A: finish layer-0 partial with x(t) ----
    float p0 = carry;
    p0 = fmaf(wx[0], xq.x, p0);
    p0 = fmaf(wx[1], xq.y, p0);
    p0 = fmaf(wx[2], xq.z, p0);
    p0 = fmaf(wx[3], xq.w, p0);
    part0[tid] = p0;
    __syncthreads();

    // prefetch x(t+1) — consumed ~400 cycles later
    {
      const int tn = (t + 1 < TT) ? (t + 1) : (TT - 1);
      xq = *(const float4*)(xb + tn * DD);
    }

    // ---- update layer-0 cell (redundant in every wave, local to thread) ----
    {
      const float pi = part0[lane]       + part0[256 + lane];
      const float pf = part0[64 + lane]  + part0[320 + lane];
      const float pg = part0[128 + lane] + part0[384 + lane];
      const float po = part0[192 + lane] + part0[448 + lane];
      const float gi = sigm(pi), gf = sigm(pf), gg = tanh_fast(pg), go = sigm(po);
      c0 = fmaf(gf, c0, gi * gg);
      h0 = go * tanh_fast(c0);
    }

    // ---- phase C: layer-1 partial + next step's Whh0 partial ----
    float2 a01 = make_float2(bias1, bias0);  // (p1, carry_next)
    float  p1b = 0.0f;
    if (half == 0) { PHASE_C(0) } else { PHASE_C(32) }
    part1[tid] = a01.x + p1b;
    carry = a01.y;
    __syncthreads();

    // ---- update layer-1 cell ----
    {
      const float pi = part1[lane]       + part1[256 + lane];
      const float pf = part1[64 + lane]  + part1[320 + lane];
      const float pg = part1[128 + lane] + part1[384 + lane];
      const float po = part1[192 + lane] + part1[448 + lane];
      const float gi = sigm(pi), gf = sigm(pf), gg = tanh_fast(pg), go = sigm(po);
      c1 = fmaf(gf, c1, gi * gg);
      h1 = go * tanh_fast(c1);
    }
  }
#undef PHASE_C

  // ---- head: out[b] = dot(h1, w_out) + b_out (wave 0's replica) ----
  if (tid < 64) {
    float v = h1 * w_out[lane];
#pragma unroll
    for (int off = 32; off; off >>= 1) v += __shfl_down(v, off);
    if (tid == 0) out[b] = v + b_out[0];
  }
}

extern "C" void kernel_launch(void* const* d_in, const int* in_sizes, int n_in,
                              void* d_out, int out_size, void* d_ws, size_t ws_size,
                              hipStream_t stream) {
  const float* x     = (const float*)d_in[0];
  const float* w_ih0 = (const float*)d_in[1];
  const float* w_hh0 = (const float*)d_in[2];
  const float* b_ih0 = (const float*)d_in[3];
  const float* b_hh0 = (const float*)d_in[4];
  const float* w_ih1 = (const float*)d_in[5];
  const float* w_hh1 = (const float*)d_in[6];
  const float* b_ih1 = (const float*)d_in[7];
  const float* b_hh1 = (const float*)d_in[8];
  const float* w_out = (const float*)d_in[9];
  const float* b_out = (const float*)d_in[10];
  float* out = (float*)d_out;

  lstm2_fused<<<dim3(BB), dim3(512), 0, stream>>>(
      x, w_ih0, w_hh0, b_ih0, b_hh0,
      w_ih1, w_hh1, b_ih1, b_hh1,
      w_out, b_out, out);
}